// Round 3
// baseline (14509.126 us; speedup 1.0000x reference)
//
#include <hip/hip_runtime.h>
#include <hip/hip_cooperative_groups.h>

namespace cg = cooperative_groups;

// ---------------- problem constants ----------------
#define Bn 32
#define Tn 64
#define Pn 196
#define ENCD 2048
#define DECD 512
#define ATTD 512
#define XDIM 2304

typedef unsigned short u16;
typedef __attribute__((ext_vector_type(8))) short bf16x8;
typedef __attribute__((ext_vector_type(4))) float f32x4;

static __device__ __forceinline__ u16 f2bf(float f){
  unsigned int u = __float_as_uint(f);
  unsigned int r = u + 0x7FFFu + ((u >> 16) & 1u);
  return (u16)(r >> 16);
}
static __device__ __forceinline__ float bf2f(u16 u){
  return __uint_as_float(((unsigned int)u) << 16);
}

// ---------------- output offsets (floats) ----------------
#define O_PRED   0
#define O_STOP   4096
#define O_SEQOFF 6144
#define O_LEN    10240
#define O_ALPHA  10272
#define O_SORT   411680

// ---------------- ws offsets: float/int region ----------------
#define WS_SORT   0         // int[32]
#define WS_LEN    32        // int[32]
#define WS_C      64        // fp32 [32][512]
#define WS_PA     16448     // fp32 [32][4608] (att2 0..511 | gateRaw 512..2559 | hh 2560..4607)
#define WS_GP     163904    // fp32 [2][32][2048]
#define WS_ENCM   294976    // fp32 [32][2048]
#define WS_EMB0   360512    // fp32 [32][256]
// float region ends at 368704 floats = 1,474,816 B  (< u16 base @ 1,600,000 B)

// ---------------- ws offsets: u16 (bf16) region, index from (u16*)d_ws ----------------
#define US_H      800000                 // [32][512]
#define US_XA     816384                 // [32][2304]
#define US_EMBBF  890112                 // [32][64][256]
#define US_ATT1   1414400                // [6272][512]
#define US_ENC    4625664                // [6272][2048] sorted
#define US_WAP    17470720               // [4624][512]: Wdec|Wfb|Whh|Wfc(2)|Wstop|pad
#define US_WIH    19838208               // [2048][2304]
#define US_WEA    24556800               // [512][2048]   (end 25,605,376 u16 = 51.2 MB)
#define US_PATCH  17470720               // [2048][3072] ALIAS over WAP+WIH (consumed before cvtall)

// ============ prep: stable descending sort ============
__global__ void k_prep(const int* __restrict__ caplen, int* __restrict__ ws_sort,
                       int* __restrict__ ws_len, float* __restrict__ out){
  __shared__ int len[32];
  int i = threadIdx.x;
  if (i < 32) len[i] = caplen[i];
  __syncthreads();
  if (i < 32){
    int li = len[i], r = 0;
    for (int j = 0; j < 32; j++){
      int lj = len[j];
      r += (lj > li) || (lj == li && j < i);
    }
    ws_sort[r] = i;
    ws_len[r]  = li;
    out[O_LEN + r]  = (float)li;
    out[O_SORT + r] = (float)i;
  }
}

__global__ void k_seqoff(const float* __restrict__ seqoff, const int* __restrict__ ws_sort,
                         float* __restrict__ out){
  int idx = blockIdx.x*256 + threadIdx.x;
  int b = idx >> 7, r = idx & 127;
  out[O_SEQOFF + idx] = seqoff[ws_sort[b]*128 + r];
}

// ============ enc -> sorted bf16 [6272][2048] ============
__global__ void k_encbf(const float* __restrict__ enc, const int* __restrict__ srt,
                        u16* __restrict__ dst){
  int m = blockIdx.x;
  int b = m / 196, p = m - b*196;
  const float* src = enc + ((size_t)srt[b]*196 + p)*ENCD;
  u16* d = dst + (size_t)m*ENCD;
  int i = threadIdx.x*8;
  float4 v0 = *(const float4*)(src + i);
  float4 v1 = *(const float4*)(src + i + 4);
  bf16x8 s;
  s[0]=(short)f2bf(v0.x); s[1]=(short)f2bf(v0.y); s[2]=(short)f2bf(v0.z); s[3]=(short)f2bf(v0.w);
  s[4]=(short)f2bf(v1.x); s[5]=(short)f2bf(v1.y); s[6]=(short)f2bf(v1.z); s[7]=(short)f2bf(v1.w);
  *(bf16x8*)(d + i) = s;
}

// ============ enc.mean over p (reads sorted bf16) ============
__global__ void k_encmean(const u16* __restrict__ encbf, float* __restrict__ encm){
  int b = blockIdx.x >> 3, dc = blockIdx.x & 7;
  int d = dc*256 + threadIdx.x;
  const u16* ep = encbf + (size_t)(b*196)*ENCD + d;
  float s = 0.f;
  #pragma unroll 4
  for (int p = 0; p < Pn; p++) s += bf2f(ep[(size_t)p*ENCD]);
  encm[b*ENCD + d] = s * (1.f/196.f);
}

// ============ patch extraction -> bf16 [2048][3072] ============
__global__ void k_patch(const float* __restrict__ imgs, const int* __restrict__ seq,
                        const int* __restrict__ srt, u16* __restrict__ patches){
  int blk = blockIdx.x; int b = blk>>6, t = blk&63;
  int sb = srt[b];
  int x0 = seq[(sb*64+t)*2 + 0], y0 = seq[(sb*64+t)*2 + 1];
  const float* img = imgs + (size_t)sb*3*512*512;
  u16* dst = patches + (size_t)(b*64+t)*3072;
  for (int idx = threadIdx.x; idx < 3072; idx += 256){
    int c = idx>>10, rem = idx&1023, i = rem>>5, j = rem&31;
    int yy = y0 + i - 24, xx = x0 + j - 24;
    float v = 0.f;
    if ((unsigned)yy < 512u && (unsigned)xx < 512u) v = img[((size_t)c*512 + yy)*512 + xx];
    dst[idx] = f2bf(v);
  }
}

// ============ embed GEMM (MFMA): emb = patches @ W_pe^T + b_pe ============
// grid 128 = 32 b * 4 nq; per wave: ntile nq*4+wv, 4 mtiles
__global__ __launch_bounds__(256) void k_embedv2(const u16* __restrict__ patches,
    const float* __restrict__ W_pe, const float* __restrict__ b_pe,
    u16* __restrict__ embbf, float* __restrict__ emb0){
  int b = blockIdx.x >> 2, nq = blockIdx.x & 3;
  __shared__ u16 A[64*264];
  int tid = threadIdx.x, wv = tid>>6, lane = tid&63, lr = lane&15, lh = lane>>4;
  int n0 = (nq*4 + wv)*16;
  f32x4 acc[4];
  #pragma unroll
  for (int mt = 0; mt < 4; mt++) acc[mt] = (f32x4){0,0,0,0};
  for (int kc = 0; kc < 12; kc++){
    __syncthreads();
    {
      int row = tid>>2, seg = tid&3;
      const u16* src = patches + (size_t)(b*64 + row)*3072 + kc*256 + seg*64;
      #pragma unroll
      for (int i = 0; i < 8; i++)
        *(bf16x8*)&A[row*264 + seg*64 + i*8] = *(const bf16x8*)(src + i*8);
    }
    __syncthreads();
    #pragma unroll
    for (int ki = 0; ki < 8; ki++){
      const float* wp = W_pe + (size_t)(n0+lr)*3072 + kc*256 + ki*32 + lh*8;
      float4 f0 = *(const float4*)wp, f1 = *(const float4*)(wp + 4);
      bf16x8 bv;
      bv[0]=(short)f2bf(f0.x); bv[1]=(short)f2bf(f0.y); bv[2]=(short)f2bf(f0.z); bv[3]=(short)f2bf(f0.w);
      bv[4]=(short)f2bf(f1.x); bv[5]=(short)f2bf(f1.y); bv[6]=(short)f2bf(f1.z); bv[7]=(short)f2bf(f1.w);
      #pragma unroll
      for (int mt = 0; mt < 4; mt++){
        bf16x8 av = *(const bf16x8*)&A[(mt*16 + lr)*264 + ki*32 + lh*8];
        acc[mt] = __builtin_amdgcn_mfma_f32_16x16x32_bf16(av, bv, acc[mt], 0, 0, 0);
      }
    }
  }
  float bias = b_pe[n0 + lr];
  #pragma unroll
  for (int mt = 0; mt < 4; mt++){
    #pragma unroll
    for (int r = 0; r < 4; r++){
      int ml = mt*16 + lh*4 + r;
      float val = acc[mt][r] + bias;
      embbf[(size_t)(b*64 + ml)*256 + n0 + lr] = f2bf(val);
      if (ml == 0) emb0[b*256 + n0 + lr] = val;
    }
  }
}

// ============ fp32 -> bf16 weight converts (one kernel, range ladder) ============
__global__ void k_cvtall(const float* __restrict__ Wdec, const float* __restrict__ Wfb,
    const float* __restrict__ Whh, const float* __restrict__ Wfc, const float* __restrict__ Wstop,
    const float* __restrict__ Wea, const float* __restrict__ Wih,
    u16* __restrict__ WAPd, u16* __restrict__ WEAd, u16* __restrict__ WIHd){
  int blk = blockIdx.x;
  const float* src; u16* dst; long off; long n;
  if      (blk < 256)  { src=Wdec;  dst=WAPd;          off=(long)blk*1024;        n=262144; }
  else if (blk < 1280) { src=Wfb;   dst=WAPd+262144;   off=(long)(blk-256)*1024;  n=1048576; }
  else if (blk < 2304) { src=Whh;   dst=WAPd+1310720;  off=(long)(blk-1280)*1024; n=1048576; }
  else if (blk < 2305) { src=Wfc;   dst=WAPd+2359296;  off=0;                     n=1024; }
  else if (blk < 2306) { src=Wstop; dst=WAPd+2359808;  off=0;                     n=512; }
  else if (blk < 2313) { src=0;     dst=WAPd+2360320;  off=(long)(blk-2306)*1024; n=6656; }
  else if (blk < 3337) { src=Wea;   dst=WEAd;          off=(long)(blk-2313)*1024; n=1048576; }
  else                 { src=Wih;   dst=WIHd;          off=(long)(blk-3337)*1024; n=4718592; }
  long i = off + (long)threadIdx.x*4;
  #pragma unroll
  for (int q = 0; q < 4; q++){
    long e = i + q;
    if (e < n) dst[e] = src ? f2bf(src[e]) : (u16)0;
  }
}

// ============ att1 (MFMA, LDS-staged A): [6272][2048]bf16 @ Wea^T -> bf16 ============
// grid 98 blocks; block handles 64 m rows x all 512 n
__global__ __launch_bounds__(256) void k_att1v2(const u16* __restrict__ encbf,
    const u16* __restrict__ Wea, const float* __restrict__ bea, u16* __restrict__ att1){
  int m0 = blockIdx.x*64;
  __shared__ u16 A[64*136];
  int tid = threadIdx.x, wv = tid>>6, lane = tid&63, lr = lane&15, lh = lane>>4;
  f32x4 acc[4][8];
  #pragma unroll
  for (int mt = 0; mt < 4; mt++)
    #pragma unroll
    for (int nt = 0; nt < 8; nt++) acc[mt][nt] = (f32x4){0,0,0,0};
  for (int kc = 0; kc < 16; kc++){
    __syncthreads();
    {
      int row = tid>>2, seg = tid&3;
      const u16* src = encbf + (size_t)(m0 + row)*2048 + kc*128 + seg*32;
      #pragma unroll
      for (int i = 0; i < 4; i++)
        *(bf16x8*)&A[row*136 + seg*32 + i*8] = *(const bf16x8*)(src + i*8);
    }
    __syncthreads();
    #pragma unroll
    for (int ki = 0; ki < 4; ki++){
      bf16x8 av[4];
      #pragma unroll
      for (int mt = 0; mt < 4; mt++)
        av[mt] = *(const bf16x8*)&A[(mt*16 + lr)*136 + ki*32 + lh*8];
      #pragma unroll
      for (int nt = 0; nt < 8; nt++){
        const u16* wp = Wea + (size_t)(wv*128 + nt*16 + lr)*2048 + kc*128 + ki*32 + lh*8;
        bf16x8 bv = *(const bf16x8*)wp;
        #pragma unroll
        for (int mt = 0; mt < 4; mt++)
          acc[mt][nt] = __builtin_amdgcn_mfma_f32_16x16x32_bf16(av[mt], bv, acc[mt][nt], 0, 0, 0);
      }
    }
  }
  #pragma unroll
  for (int nt = 0; nt < 8; nt++){
    int n = wv*128 + nt*16 + lr;
    float bias = bea[n];
    #pragma unroll
    for (int mt = 0; mt < 4; mt++){
      #pragma unroll
      for (int r = 0; r < 4; r++){
        int m = m0 + mt*16 + lh*4 + r;
        att1[(size_t)m*512 + n] = f2bf(acc[mt][nt][r] + bias);
      }
    }
  }
}

// ============ h,c init (fp32; h stored bf16) ============
__global__ __launch_bounds__(256) void k_init(const float* __restrict__ encm, const float* __restrict__ emb0,
    const float* __restrict__ Wh, const float* __restrict__ bh,
    const float* __restrict__ Wc, const float* __restrict__ bc,
    u16* __restrict__ h_bf, float* __restrict__ c){
  int mat = blockIdx.x >> 4, jb = blockIdx.x & 15;
  const float* W    = mat ? Wc : Wh;
  const float* bias = mat ? bc : bh;
  int j0 = jb*32;
  __shared__ float XT[256*36];
  int bq = threadIdx.x & 7, jq = threadIdx.x >> 3;
  float acc[4] = {0.f,0.f,0.f,0.f};
  for (int ch = 0; ch < 9; ch++){
    int k0 = ch*256;
    __syncthreads();
    {
      int m = threadIdx.x >> 3, kq8 = threadIdx.x & 7;
      #pragma unroll
      for (int i = 0; i < 8; i++){
        int kq = kq8 + i*8;
        int k = k0 + kq*4;
        float4 v;
        if (k < 2048) v = *(const float4*)&encm[m*ENCD + k];
        else          v = *(const float4*)&emb0[m*256 + (k - 2048)];
        XT[(4*kq+0)*36+m]=v.x; XT[(4*kq+1)*36+m]=v.y; XT[(4*kq+2)*36+m]=v.z; XT[(4*kq+3)*36+m]=v.w;
      }
    }
    __syncthreads();
    int j = j0 + jq;
    const float* wr = W + (size_t)j*XDIM + k0;
    #pragma unroll 2
    for (int k4 = 0; k4 < 64; k4++){
      float4 wv = *(const float4*)(wr + k4*4);
      float4 x0 = *(float4*)&XT[(k4*4+0)*36 + bq*4];
      float4 x1 = *(float4*)&XT[(k4*4+1)*36 + bq*4];
      float4 x2 = *(float4*)&XT[(k4*4+2)*36 + bq*4];
      float4 x3 = *(float4*)&XT[(k4*4+3)*36 + bq*4];
      acc[0] += x0.x*wv.x + x1.x*wv.y + x2.x*wv.z + x3.x*wv.w;
      acc[1] += x0.y*wv.x + x1.y*wv.y + x2.y*wv.z + x3.y*wv.w;
      acc[2] += x0.z*wv.x + x1.z*wv.y + x2.z*wv.z + x3.z*wv.w;
      acc[3] += x0.w*wv.x + x1.w*wv.y + x2.w*wv.z + x3.w*wv.w;
    }
  }
  #pragma unroll
  for (int bb = 0; bb < 4; bb++){
    float v = acc[bb] + bias[j0 + jq];
    int row = bq*4 + bb;
    if (mat == 0) h_bf[row*DECD + j0 + jq] = f2bf(v);
    else          c[row*DECD + j0 + jq] = v;
  }
}

// ============ THE LOOP: one cooperative kernel, 4 grid syncs per step ============
struct LoopArgs {
  float* pA; float* gP; float* c; u16* hbf; u16* xa;
  const u16* att1; const u16* encbf; const u16* embbf;
  const u16* WAP; const u16* WIH;
  const float* bdec; const float* wfull; const float* bfull; const float* bfb;
  const float* bih; const float* bhh; const float* bfc; const float* bstop;
  const int* len; float* out;
};

__global__ __launch_bounds__(256) void k_loop(LoopArgs p){
  cg::grid_group gg = cg::this_grid();
  int wg = blockIdx.x, tid = threadIdx.x;
  int wv = tid>>6, lane = tid&63, lr = lane&15, lh = lane>>4;
  __shared__ float a2f[512], wff[512], sc[256], evs[256], red[4], bcx[2];

  for (int t = 0; t <= 64; t++){
    // ---------- Phase A: pA = h @ [Wdec|Wfb|Whh]^T ; preds/stop for t-1 ----------
    if (wg < 73){
      int j0 = wg*64 + wv*16;
      if (j0 < 4624){
        const u16* ha = p.hbf + (size_t)lr*512 + lh*8;
        const u16* wb = p.WAP + (size_t)(j0 + lr)*512 + lh*8;
        f32x4 acc0 = {0,0,0,0}, acc1 = {0,0,0,0};
        #pragma unroll 4
        for (int k0 = 0; k0 < 512; k0 += 32){
          bf16x8 bv = *(const bf16x8*)(wb + k0);
          bf16x8 a0 = *(const bf16x8*)(ha + k0);
          bf16x8 a1 = *(const bf16x8*)(ha + 8192 + k0);
          acc0 = __builtin_amdgcn_mfma_f32_16x16x32_bf16(a0, bv, acc0, 0, 0, 0);
          acc1 = __builtin_amdgcn_mfma_f32_16x16x32_bf16(a1, bv, acc1, 0, 0, 0);
        }
        int j = j0 + lr;
        if (j < 4608){
          #pragma unroll
          for (int r = 0; r < 4; r++){
            p.pA[(size_t)(lh*4 + r)*4608 + j]      = acc0[r];
            p.pA[(size_t)(lh*4 + r + 16)*4608 + j] = acc1[r];
          }
        } else if (t > 0 && (j - 4608) < 3){
          int jj = j - 4608, tm1 = t - 1;
          #pragma unroll
          for (int r = 0; r < 4; r++){
            #pragma unroll
            for (int hb = 0; hb < 2; hb++){
              int b0 = lh*4 + r + hb*16;
              float val = hb ? acc1[r] : acc0[r];
              bool mk = tm1 < p.len[b0];
              if (jj < 2) p.out[O_PRED + ((size_t)b0*64 + tm1)*2 + jj] = mk ? val + p.bfc[jj] : 0.f;
              else        p.out[O_STOP + (size_t)b0*64 + tm1] =
                            mk ? 1.f/(1.f + expf(-(val + p.bstop[0]))) : 0.f;
            }
          }
        }
      }
    }
    if (t == 64) break;
    gg.sync();

    // ---------- Phase B: scores + softmax + awe + gate -> xa ; alphas ----------
    if (wg < 64){
      int b = wg >> 1, half = wg & 1;
      bool active = t < p.len[b];
      if (active){
        for (int a = tid; a < 512; a += 256){
          a2f[a] = p.pA[(size_t)b*4608 + a] + p.bdec[a];
          wff[a] = p.wfull[a];
        }
        __syncthreads();
        {
          int pl = tid >> 2, ac = tid & 3;
          const float* a2p = a2f + ac*128;
          const float* wfp = wff + ac*128;
          #pragma unroll
          for (int pb = 0; pb < 4; pb++){
            int pp = pb*64 + pl;
            float acc = 0.f;
            if (pp < 196){
              const u16* row = p.att1 + ((size_t)(b*196 + pp))*512 + ac*128;
              #pragma unroll 4
              for (int i = 0; i < 16; i++){
                bf16x8 vvv = *(const bf16x8*)(row + i*8);
                #pragma unroll
                for (int q = 0; q < 8; q++)
                  acc += fmaxf(bf2f((u16)vvv[q]) + a2p[i*8+q], 0.f) * wfp[i*8+q];
              }
            }
            acc += __shfl_xor(acc, 1);
            acc += __shfl_xor(acc, 2);
            if (pp < 196 && ac == 0) sc[pp] = acc + p.bfull[0];
          }
        }
        __syncthreads();
        float s = (tid < 196) ? sc[tid] : -1e30f;
        float m = s;
        #pragma unroll
        for (int o = 32; o; o >>= 1) m = fmaxf(m, __shfl_down(m, o));
        if (lane == 0) red[wv] = m;
        __syncthreads();
        if (tid == 0) bcx[0] = fmaxf(fmaxf(red[0],red[1]), fmaxf(red[2],red[3]));
        __syncthreads();
        float smax = bcx[0];
        float e = (tid < 196) ? expf(s - smax) : 0.f;
        evs[tid] = e;
        float sm = e;
        #pragma unroll
        for (int o = 32; o; o >>= 1) sm += __shfl_down(sm, o);
        if (lane == 0) red[wv] = sm;
        __syncthreads();
        if (tid == 0) bcx[1] = red[0]+red[1]+red[2]+red[3];
        __syncthreads();
        float ssum = bcx[1];

        const u16* ep0 = p.encbf + (size_t)(b*196)*2048;
        #pragma unroll
        for (int dc = 0; dc < 4; dc++){
          int d = half*1024 + dc*256 + tid;
          const u16* ep = ep0 + d;
          float q0=0.f, q1=0.f, q2=0.f, q3=0.f;
          #pragma unroll 2
          for (int pp = 0; pp < 196; pp += 4){
            q0 += evs[pp+0]*bf2f(ep[(size_t)(pp+0)*2048]);
            q1 += evs[pp+1]*bf2f(ep[(size_t)(pp+1)*2048]);
            q2 += evs[pp+2]*bf2f(ep[(size_t)(pp+2)*2048]);
            q3 += evs[pp+3]*bf2f(ep[(size_t)(pp+3)*2048]);
          }
          float awe = ((q0+q1)+(q2+q3)) / ssum;
          float gp = p.pA[(size_t)b*4608 + 512 + d] + p.bfb[d];
          float gate = 1.f/(1.f + expf(-gp));
          p.xa[(size_t)b*2304 + d] = f2bf(gate*awe);
        }
        if (half == 1) p.xa[(size_t)b*2304 + 2048 + tid] = p.embbf[((size_t)b*64 + t)*256 + tid];
        if (half == 0 && tid < 196) p.out[O_ALPHA + ((size_t)b*64 + t)*196 + tid] = evs[tid]/ssum;
      } else {
        if (half == 0 && tid < 196) p.out[O_ALPHA + ((size_t)b*64 + t)*196 + tid] = 0.f;
      }
    }
    gg.sync();

    // ---------- Phase C: gP = xa @ Wih^T (K-split 2) [+ hh + biases on kc=0] ----------
    if (wg < 64){
      int jg = wg >> 1, kc = wg & 1;
      int j0 = jg*64 + wv*16;
      const u16* xp = p.xa + (size_t)lr*2304 + kc*1152 + lh*8;
      const u16* wp = p.WIH + (size_t)(j0 + lr)*2304 + kc*1152 + lh*8;
      f32x4 acc0 = {0,0,0,0}, acc1 = {0,0,0,0};
      #pragma unroll 4
      for (int k0 = 0; k0 < 1152; k0 += 32){
        bf16x8 bv = *(const bf16x8*)(wp + k0);
        bf16x8 a0 = *(const bf16x8*)(xp + k0);
        bf16x8 a1 = *(const bf16x8*)(xp + 16*2304 + k0);
        acc0 = __builtin_amdgcn_mfma_f32_16x16x32_bf16(a0, bv, acc0, 0, 0, 0);
        acc1 = __builtin_amdgcn_mfma_f32_16x16x32_bf16(a1, bv, acc1, 0, 0, 0);
      }
      int j = j0 + lr;
      if (kc == 0){
        float base = p.bih[j] + p.bhh[j];
        #pragma unroll
        for (int r = 0; r < 4; r++){
          int b0 = lh*4 + r;
          p.gP[(size_t)b0*2048 + j]      = acc0[r] + base + p.pA[(size_t)b0*4608 + 2560 + j];
          p.gP[(size_t)(b0+16)*2048 + j] = acc1[r] + base + p.pA[(size_t)(b0+16)*4608 + 2560 + j];
        }
      } else {
        #pragma unroll
        for (int r = 0; r < 4; r++){
          int b0 = lh*4 + r;
          p.gP[65536 + (size_t)b0*2048 + j]      = acc0[r];
          p.gP[65536 + (size_t)(b0+16)*2048 + j] = acc1[r];
        }
      }
    }
    gg.sync();

    // ---------- Phase D: LSTM state update ----------
    if (wg < 32){
      int b = wg;
      if (t < p.len[b]){
        for (int j = tid; j < 512; j += 256){
          float g0 = p.gP[(size_t)b*2048 + j]        + p.gP[65536 + (size_t)b*2048 + j];
          float g1 = p.gP[(size_t)b*2048 + 512 + j]  + p.gP[65536 + (size_t)b*2048 + 512 + j];
          float g2 = p.gP[(size_t)b*2048 + 1024 + j] + p.gP[65536 + (size_t)b*2048 + 1024 + j];
          float g3 = p.gP[(size_t)b*2048 + 1536 + j] + p.gP[65536 + (size_t)b*2048 + 1536 + j];
          float ig = 1.f/(1.f + expf(-g0));
          float fg = 1.f/(1.f + expf(-g1));
          float gt = tanhf(g2);
          float og = 1.f/(1.f + expf(-g3));
          float cn = fg*p.c[b*512 + j] + ig*gt;
          float hv = og*tanhf(cn);
          p.c[b*512 + j] = cn;
          p.hbf[b*512 + j] = f2bf(hv);
        }
      }
    }
    gg.sync();
  }
}

// ================= host launcher =================
extern "C" void kernel_launch(void* const* d_in, const int* in_sizes, int n_in,
                              void* d_out, int out_size, void* d_ws, size_t ws_size,
                              hipStream_t stream){
  (void)in_sizes; (void)n_in; (void)out_size; (void)ws_size;
  const float* enc_out   = (const float*)d_in[0];
  const float* imgs      = (const float*)d_in[1];
  const int*   seq       = (const int*)d_in[2];
  const float* seqoff    = (const float*)d_in[3];
  const int*   caplen    = (const int*)d_in[4];
  const float* W_pe      = (const float*)d_in[5];
  const float* b_pe      = (const float*)d_in[6];
  const float* W_enc_att = (const float*)d_in[7];
  const float* b_enc_att = (const float*)d_in[8];
  const float* W_dec_att = (const float*)d_in[9];
  const float* b_dec_att = (const float*)d_in[10];
  const float* w_full    = (const float*)d_in[11];
  const float* b_full    = (const float*)d_in[12];
  const float* W_init_h  = (const float*)d_in[13];
  const float* b_init_h  = (const float*)d_in[14];
  const float* W_init_c  = (const float*)d_in[15];
  const float* b_init_c  = (const float*)d_in[16];
  const float* W_fb      = (const float*)d_in[17];
  const float* b_fb      = (const float*)d_in[18];
  const float* W_ih      = (const float*)d_in[19];
  const float* b_ih      = (const float*)d_in[20];
  const float* W_hh      = (const float*)d_in[21];
  const float* b_hh      = (const float*)d_in[22];
  const float* W_fc      = (const float*)d_in[23];
  const float* b_fc      = (const float*)d_in[24];
  const float* W_stop    = (const float*)d_in[25];
  const float* b_stop    = (const float*)d_in[26];

  float* out = (float*)d_out;
  float* ws  = (float*)d_ws;
  int*   wsi = (int*)d_ws;
  u16*   us  = (u16*)d_ws;

  k_prep<<<1, 64, 0, stream>>>(caplen, wsi + WS_SORT, wsi + WS_LEN, out);
  k_seqoff<<<16, 256, 0, stream>>>(seqoff, wsi + WS_SORT, out);
  k_encbf<<<6272, 256, 0, stream>>>(enc_out, wsi + WS_SORT, us + US_ENC);
  k_encmean<<<256, 256, 0, stream>>>(us + US_ENC, ws + WS_ENCM);
  k_patch<<<2048, 256, 0, stream>>>(imgs, seq, wsi + WS_SORT, us + US_PATCH);
  k_embedv2<<<128, 256, 0, stream>>>(us + US_PATCH, W_pe, b_pe, us + US_EMBBF, ws + WS_EMB0);
  k_cvtall<<<7945, 256, 0, stream>>>(W_dec_att, W_fb, W_hh, W_fc, W_stop, W_enc_att, W_ih,
                                     us + US_WAP, us + US_WEA, us + US_WIH);
  k_att1v2<<<98, 256, 0, stream>>>(us + US_ENC, us + US_WEA, b_enc_att, us + US_ATT1);
  k_init<<<32, 256, 0, stream>>>(ws + WS_ENCM, ws + WS_EMB0, W_init_h, b_init_h, W_init_c, b_init_c,
                                 us + US_H, ws + WS_C);

  LoopArgs la;
  la.pA = ws + WS_PA; la.gP = ws + WS_GP; la.c = ws + WS_C;
  la.hbf = us + US_H; la.xa = us + US_XA;
  la.att1 = us + US_ATT1; la.encbf = us + US_ENC; la.embbf = us + US_EMBBF;
  la.WAP = us + US_WAP; la.WIH = us + US_WIH;
  la.bdec = b_dec_att; la.wfull = w_full; la.bfull = b_full; la.bfb = b_fb;
  la.bih = b_ih; la.bhh = b_hh; la.bfc = b_fc; la.bstop = b_stop;
  la.len = wsi + WS_LEN; la.out = out;
  void* ka[1] = { (void*)&la };
  hipLaunchCooperativeKernel((const void*)k_loop, dim3(256), dim3(256), ka, 0, stream);
}

// Round 4
// 5630.922 us; speedup vs baseline: 2.5767x; 2.5767x over previous
//
#include <hip/hip_runtime.h>

// ---------------- problem constants ----------------
#define Bn 32
#define Tn 64
#define Pn 196
#define ENCD 2048
#define DECD 512
#define ATTD 512
#define XDIM 2304
#define NWG 256

typedef unsigned short u16;
typedef __attribute__((ext_vector_type(8))) short bf16x8;
typedef __attribute__((ext_vector_type(4))) float f32x4;

#define MF(a,b,c) __builtin_amdgcn_mfma_f32_16x16x32_bf16(a,b,c,0,0,0)

static __device__ __forceinline__ u16 f2bf(float f){
  unsigned int u = __float_as_uint(f);
  unsigned int r = u + 0x7FFFu + ((u >> 16) & 1u);
  return (u16)(r >> 16);
}
static __device__ __forceinline__ float bf2f(u16 u){
  return __uint_as_float(((unsigned int)u) << 16);
}

// coherent (agent-scope, L2-bypassing) helpers
static __device__ __forceinline__ void cstore_u32(unsigned* p, unsigned v){
  __hip_atomic_store(p, v, __ATOMIC_RELAXED, __HIP_MEMORY_SCOPE_AGENT);
}
static __device__ __forceinline__ unsigned cload_u32(const unsigned* p){
  return __hip_atomic_load((unsigned*)p, __ATOMIC_RELAXED, __HIP_MEMORY_SCOPE_AGENT);
}
static __device__ __forceinline__ void cstore_f32(float* p, float v){
  cstore_u32((unsigned*)p, __float_as_uint(v));
}
static __device__ __forceinline__ float cload_f32(const float* p){
  return __uint_as_float(cload_u32((const unsigned*)p));
}
static __device__ __forceinline__ unsigned long long cload_u64(const unsigned long long* p){
  return __hip_atomic_load((unsigned long long*)p, __ATOMIC_RELAXED, __HIP_MEMORY_SCOPE_AGENT);
}
static __device__ __forceinline__ bf16x8 cload_bf8(const u16* p){
  union { unsigned long long q[2]; bf16x8 v; } u;
  u.q[0] = cload_u64((const unsigned long long*)p);
  u.q[1] = cload_u64((const unsigned long long*)(p + 4));
  return u.v;
}

// custom grid barrier: no acquire fence -> L2 stays warm
static __device__ __forceinline__ void gbar(unsigned* cnt, unsigned target){
  __syncthreads();
  if (threadIdx.x == 0){
    __hip_atomic_fetch_add(cnt, 1u, __ATOMIC_RELEASE, __HIP_MEMORY_SCOPE_AGENT);
    while (__hip_atomic_load(cnt, __ATOMIC_RELAXED, __HIP_MEMORY_SCOPE_AGENT) < target)
      __builtin_amdgcn_s_sleep(2);
  }
  asm volatile("" ::: "memory");
  __syncthreads();
}

// ---------------- output offsets (floats) ----------------
#define O_PRED   0
#define O_STOP   4096
#define O_SEQOFF 6144
#define O_LEN    10240
#define O_ALPHA  10272
#define O_SORT   411680

// ---------------- ws: f32/int region (f32 indices) ----------------
#define WS_SORT   0        // int[32]
#define WS_LEN    32       // int[32]
#define WS_BAR    64       // unsigned counter (padded)
#define WS_C      128      // f32 [32][512]
#define WS_PA     16512    // f32 [32][2560]  (att2 0..511 | gateRaw 512..2559)
#define WS_SCORES 98432    // f32 [32][256]
#define WS_ENCM   106624   // f32 [32][2048]
#define WS_EMB0   172160   // f32 [32][256]
#define WS_BCOMB  180352   // f32 [2048]
// ---------------- ws: u16 region (u16 indices from (u16*)d_ws) ----------------
#define US_H0     524288                  // [32][512]
#define US_H1     540672
#define US_AXA    557056                  // [32][2048]
#define US_EMBBF  622592                  // [32][64][256]
#define US_ATT1   1146880                 // [6272][512]
#define US_ENC    4358144                 // [6272][2048]
#define US_WEA    17203200                // [512][2048]
#define US_WAP    18251776                // [2688][512] Wdec|Wfb|Wfc|Wstop|pad
#define US_WIHE   19628032                // [2048][256]  (j'-interleaved)
#define US_WHH2   20152320                // [2048][512]  (j'-interleaved)
#define US_WIH2   21200896                // [2048][2048] (j'-interleaved)
#define US_GEMB   25395200                // [32][64][2048] bf16
#define US_PATCH  21200896                // [2048][3072] ALIAS over WIH2+GEMB (consumed first)

// ============ prep: stable descending sort + barrier zero ============
__global__ void k_prep(const int* __restrict__ caplen, int* __restrict__ ws_sort,
                       int* __restrict__ ws_len, unsigned* __restrict__ bar,
                       float* __restrict__ out){
  __shared__ int len[32];
  int i = threadIdx.x;
  if (i == 0) *bar = 0u;
  if (i < 32) len[i] = caplen[i];
  __syncthreads();
  if (i < 32){
    int li = len[i], r = 0;
    for (int j = 0; j < 32; j++){
      int lj = len[j];
      r += (lj > li) || (lj == li && j < i);
    }
    ws_sort[r] = i;
    ws_len[r]  = li;
    out[O_LEN + r]  = (float)li;
    out[O_SORT + r] = (float)i;
  }
}

__global__ void k_seqoff(const float* __restrict__ seqoff, const int* __restrict__ ws_sort,
                         float* __restrict__ out){
  int idx = blockIdx.x*256 + threadIdx.x;
  int b = idx >> 7, r = idx & 127;
  out[O_SEQOFF + idx] = seqoff[ws_sort[b]*128 + r];
}

// ============ enc -> sorted bf16 ============
__global__ void k_encbf(const float* __restrict__ enc, const int* __restrict__ srt,
                        u16* __restrict__ dst){
  int m = blockIdx.x;
  int b = m / 196, p = m - b*196;
  const float* src = enc + ((size_t)srt[b]*196 + p)*ENCD;
  u16* d = dst + (size_t)m*ENCD;
  int i = threadIdx.x*8;
  float4 v0 = *(const float4*)(src + i);
  float4 v1 = *(const float4*)(src + i + 4);
  bf16x8 s;
  s[0]=(short)f2bf(v0.x); s[1]=(short)f2bf(v0.y); s[2]=(short)f2bf(v0.z); s[3]=(short)f2bf(v0.w);
  s[4]=(short)f2bf(v1.x); s[5]=(short)f2bf(v1.y); s[6]=(short)f2bf(v1.z); s[7]=(short)f2bf(v1.w);
  *(bf16x8*)(d + i) = s;
}

__global__ void k_encmean(const u16* __restrict__ encbf, float* __restrict__ encm){
  int b = blockIdx.x >> 3, dc = blockIdx.x & 7;
  int d = dc*256 + threadIdx.x;
  const u16* ep = encbf + (size_t)(b*196)*ENCD + d;
  float s = 0.f;
  #pragma unroll 4
  for (int p = 0; p < Pn; p++) s += bf2f(ep[(size_t)p*ENCD]);
  encm[b*ENCD + d] = s * (1.f/196.f);
}

// ============ patch extraction -> bf16 ============
__global__ void k_patch(const float* __restrict__ imgs, const int* __restrict__ seq,
                        const int* __restrict__ srt, u16* __restrict__ patches){
  int blk = blockIdx.x; int b = blk>>6, t = blk&63;
  int sb = srt[b];
  int x0 = seq[(sb*64+t)*2 + 0], y0 = seq[(sb*64+t)*2 + 1];
  const float* img = imgs + (size_t)sb*3*512*512;
  u16* dst = patches + (size_t)(b*64+t)*3072;
  for (int idx = threadIdx.x; idx < 3072; idx += 256){
    int c = idx>>10, rem = idx&1023, i = rem>>5, j = rem&31;
    int yy = y0 + i - 24, xx = x0 + j - 24;
    float v = 0.f;
    if ((unsigned)yy < 512u && (unsigned)xx < 512u) v = img[((size_t)c*512 + yy)*512 + xx];
    dst[idx] = f2bf(v);
  }
}

// ============ embed GEMM ============
__global__ __launch_bounds__(256) void k_embedv2(const u16* __restrict__ patches,
    const float* __restrict__ W_pe, const float* __restrict__ b_pe,
    u16* __restrict__ embbf, float* __restrict__ emb0){
  int b = blockIdx.x >> 2, nq = blockIdx.x & 3;
  __shared__ u16 A[64*264];
  int tid = threadIdx.x, wv = tid>>6, lane = tid&63, lr = lane&15, lh = lane>>4;
  int n0 = (nq*4 + wv)*16;
  f32x4 acc[4];
  #pragma unroll
  for (int mt = 0; mt < 4; mt++) acc[mt] = (f32x4){0,0,0,0};
  for (int kc = 0; kc < 12; kc++){
    __syncthreads();
    {
      int row = tid>>2, seg = tid&3;
      const u16* src = patches + (size_t)(b*64 + row)*3072 + kc*256 + seg*64;
      #pragma unroll
      for (int i = 0; i < 8; i++)
        *(bf16x8*)&A[row*264 + seg*64 + i*8] = *(const bf16x8*)(src + i*8);
    }
    __syncthreads();
    #pragma unroll
    for (int ki = 0; ki < 8; ki++){
      const float* wp = W_pe + (size_t)(n0+lr)*3072 + kc*256 + ki*32 + lh*8;
      float4 f0 = *(const float4*)wp, f1 = *(const float4*)(wp + 4);
      bf16x8 bv;
      bv[0]=(short)f2bf(f0.x); bv[1]=(short)f2bf(f0.y); bv[2]=(short)f2bf(f0.z); bv[3]=(short)f2bf(f0.w);
      bv[4]=(short)f2bf(f1.x); bv[5]=(short)f2bf(f1.y); bv[6]=(short)f2bf(f1.z); bv[7]=(short)f2bf(f1.w);
      #pragma unroll
      for (int mt = 0; mt < 4; mt++){
        bf16x8 av = *(const bf16x8*)&A[(mt*16 + lr)*264 + ki*32 + lh*8];
        acc[mt] = MF(av, bv, acc[mt]);
      }
    }
  }
  float bias = b_pe[n0 + lr];
  #pragma unroll
  for (int mt = 0; mt < 4; mt++){
    #pragma unroll
    for (int r = 0; r < 4; r++){
      int ml = mt*16 + lh*4 + r;
      float val = acc[mt][r] + bias;
      embbf[(size_t)(b*64 + ml)*256 + n0 + lr] = f2bf(val);
      if (ml == 0) emb0[b*256 + n0 + lr] = val;
    }
  }
}

// ============ weight converts: interleaved layouts ============
__global__ void k_cvt2(const float* __restrict__ Wih, const float* __restrict__ Whh,
    const float* __restrict__ Wdec, const float* __restrict__ Wfb,
    const float* __restrict__ Wfc, const float* __restrict__ Wstop,
    const float* __restrict__ Wea, const float* __restrict__ bih, const float* __restrict__ bhh,
    u16* __restrict__ WIH2, u16* __restrict__ WIHE, u16* __restrict__ WHH2,
    u16* __restrict__ WAP, u16* __restrict__ WEAd, float* __restrict__ bcomb){
  int blk = blockIdx.x, tid = threadIdx.x;
  if (blk < 2048){
    int r = blk, jp = (r & 511)*4 + (r >> 9);
    for (int i = tid; i < 2304; i += 256){
      u16 v = f2bf(Wih[(size_t)r*2304 + i]);
      if (i < 2048) WIH2[(size_t)jp*2048 + i] = v;
      else          WIHE[(size_t)jp*256 + (i - 2048)] = v;
    }
  } else if (blk < 4096){
    int r = blk - 2048, jp = (r & 511)*4 + (r >> 9);
    for (int i = tid; i < 512; i += 256)
      WHH2[(size_t)jp*512 + i] = f2bf(Whh[(size_t)r*512 + i]);
  } else if (blk < 6784){
    int j = blk - 4096;
    const float* src;
    if (j < 512) src = Wdec + (size_t)j*512;
    else if (j < 2560) src = Wfb + (size_t)(j-512)*512;
    else if (j == 2560) src = Wfc;
    else if (j == 2561) src = Wfc + 512;
    else if (j == 2562) src = Wstop;
    else src = 0;
    for (int i = tid; i < 512; i += 256)
      WAP[(size_t)j*512 + i] = src ? f2bf(src[i]) : (u16)0;
  } else if (blk < 7296){
    int r = blk - 6784;
    for (int i = tid; i < 2048; i += 256)
      WEAd[(size_t)r*2048 + i] = f2bf(Wea[(size_t)r*2048 + i]);
  } else {
    int jp = (blk - 7296)*256 + tid;
    int r = (jp & 3)*512 + (jp >> 2);
    bcomb[jp] = bih[r] + bhh[r];
  }
}

// ============ G_emb = emb @ WIHE^T (bf16) ============
__global__ __launch_bounds__(256) void k_gemb(const u16* __restrict__ embbf,
    const u16* __restrict__ WIHE, u16* __restrict__ gemb){
  int m0 = (blockIdx.x >> 3)*64, n0 = (blockIdx.x & 7)*256;
  __shared__ u16 A[64*264];
  int tid = threadIdx.x, wv = tid>>6, lane = tid&63, lr = lane&15, lh = lane>>4;
  {
    int row = tid>>2, seg = tid&3;
    const u16* src = embbf + (size_t)(m0 + row)*256 + seg*64;
    #pragma unroll
    for (int i = 0; i < 8; i++)
      *(bf16x8*)&A[row*264 + seg*64 + i*8] = *(const bf16x8*)(src + i*8);
  }
  __syncthreads();
  f32x4 acc[4][4];
  #pragma unroll
  for (int mt = 0; mt < 4; mt++)
    #pragma unroll
    for (int nt = 0; nt < 4; nt++) acc[mt][nt] = (f32x4){0,0,0,0};
  #pragma unroll
  for (int ki = 0; ki < 8; ki++){
    bf16x8 av[4];
    #pragma unroll
    for (int mt = 0; mt < 4; mt++)
      av[mt] = *(const bf16x8*)&A[(mt*16 + lr)*264 + ki*32 + lh*8];
    #pragma unroll
    for (int nt = 0; nt < 4; nt++){
      bf16x8 bv = *(const bf16x8*)&WIHE[(size_t)(n0 + wv*64 + nt*16 + lr)*256 + ki*32 + lh*8];
      #pragma unroll
      for (int mt = 0; mt < 4; mt++) acc[mt][nt] = MF(av[mt], bv, acc[mt][nt]);
    }
  }
  #pragma unroll
  for (int nt = 0; nt < 4; nt++){
    int n = n0 + wv*64 + nt*16 + lr;
    #pragma unroll
    for (int mt = 0; mt < 4; mt++)
      #pragma unroll
      for (int r = 0; r < 4; r++)
        gemb[(size_t)(m0 + mt*16 + lh*4 + r)*2048 + n] = f2bf(acc[mt][nt][r]);
  }
}

// ============ att1 (MFMA) ============
__global__ __launch_bounds__(256) void k_att1v2(const u16* __restrict__ encbf,
    const u16* __restrict__ Wea, const float* __restrict__ bea, u16* __restrict__ att1){
  int m0 = blockIdx.x*64;
  __shared__ u16 A[64*136];
  int tid = threadIdx.x, wv = tid>>6, lane = tid&63, lr = lane&15, lh = lane>>4;
  f32x4 acc[4][8];
  #pragma unroll
  for (int mt = 0; mt < 4; mt++)
    #pragma unroll
    for (int nt = 0; nt < 8; nt++) acc[mt][nt] = (f32x4){0,0,0,0};
  for (int kc = 0; kc < 16; kc++){
    __syncthreads();
    {
      int row = tid>>2, seg = tid&3;
      const u16* src = encbf + (size_t)(m0 + row)*2048 + kc*128 + seg*32;
      #pragma unroll
      for (int i = 0; i < 4; i++)
        *(bf16x8*)&A[row*136 + seg*32 + i*8] = *(const bf16x8*)(src + i*8);
    }
    __syncthreads();
    #pragma unroll
    for (int ki = 0; ki < 4; ki++){
      bf16x8 av[4];
      #pragma unroll
      for (int mt = 0; mt < 4; mt++)
        av[mt] = *(const bf16x8*)&A[(mt*16 + lr)*136 + ki*32 + lh*8];
      #pragma unroll
      for (int nt = 0; nt < 8; nt++){
        const u16* wp = Wea + (size_t)(wv*128 + nt*16 + lr)*2048 + kc*128 + ki*32 + lh*8;
        bf16x8 bv = *(const bf16x8*)wp;
        #pragma unroll
        for (int mt = 0; mt < 4; mt++) acc[mt][nt] = MF(av[mt], bv, acc[mt][nt]);
      }
    }
  }
  #pragma unroll
  for (int nt = 0; nt < 8; nt++){
    int n = wv*128 + nt*16 + lr;
    float bias = bea[n];
    #pragma unroll
    for (int mt = 0; mt < 4; mt++)
      #pragma unroll
      for (int r = 0; r < 4; r++)
        att1[(size_t)(m0 + mt*16 + lh*4 + r)*512 + n] = f2bf(acc[mt][nt][r] + bias);
  }
}

// ============ h,c init ============
__global__ __launch_bounds__(256) void k_init(const float* __restrict__ encm, const float* __restrict__ emb0,
    const float* __restrict__ Wh, const float* __restrict__ bh,
    const float* __restrict__ Wc, const float* __restrict__ bc,
    u16* __restrict__ h_bf, float* __restrict__ c){
  int mat = blockIdx.x >> 4, jb = blockIdx.x & 15;
  const float* W    = mat ? Wc : Wh;
  const float* bias = mat ? bc : bh;
  int j0 = jb*32;
  __shared__ float XT[256*36];
  int bq = threadIdx.x & 7, jq = threadIdx.x >> 3;
  float acc[4] = {0.f,0.f,0.f,0.f};
  for (int ch = 0; ch < 9; ch++){
    int k0 = ch*256;
    __syncthreads();
    {
      int m = threadIdx.x >> 3, kq8 = threadIdx.x & 7;
      #pragma unroll
      for (int i = 0; i < 8; i++){
        int kq = kq8 + i*8;
        int k = k0 + kq*4;
        float4 v;
        if (k < 2048) v = *(const float4*)&encm[m*ENCD + k];
        else          v = *(const float4*)&emb0[m*256 + (k - 2048)];
        XT[(4*kq+0)*36+m]=v.x; XT[(4*kq+1)*36+m]=v.y; XT[(4*kq+2)*36+m]=v.z; XT[(4*kq+3)*36+m]=v.w;
      }
    }
    __syncthreads();
    int j = j0 + jq;
    const float* wr = W + (size_t)j*XDIM + k0;
    #pragma unroll 2
    for (int k4 = 0; k4 < 64; k4++){
      float4 wv = *(const float4*)(wr + k4*4);
      float4 x0 = *(float4*)&XT[(k4*4+0)*36 + bq*4];
      float4 x1 = *(float4*)&XT[(k4*4+1)*36 + bq*4];
      float4 x2 = *(float4*)&XT[(k4*4+2)*36 + bq*4];
      float4 x3 = *(float4*)&XT[(k4*4+3)*36 + bq*4];
      acc[0] += x0.x*wv.x + x1.x*wv.y + x2.x*wv.z + x3.x*wv.w;
      acc[1] += x0.y*wv.x + x1.y*wv.y + x2.y*wv.z + x3.y*wv.w;
      acc[2] += x0.z*wv.x + x1.z*wv.y + x2.z*wv.z + x3.z*wv.w;
      acc[3] += x0.w*wv.x + x1.w*wv.y + x2.w*wv.z + x3.w*wv.w;
    }
  }
  #pragma unroll
  for (int bb = 0; bb < 4; bb++){
    float v = acc[bb] + bias[j0 + jq];
    int row = bq*4 + bb;
    if (mat == 0) h_bf[row*DECD + j0 + jq] = f2bf(v);
    else          c[row*DECD + j0 + jq] = v;
  }
}

// ============ persistent loop kernel ============
struct LoopP {
  unsigned* bar;
  float* pA; float* scores; float* c;
  const float* bcomb;
  u16* h0; u16* h1; u16* axa;
  const u16* att1; const u16* enc; const u16* gemb;
  const u16* WAP; const u16* WIH2; const u16* WHH2;
  const float* bdec; const float* wfull; const float* bfull; const float* bfb;
  const float* bfc; const float* bstop;
  const int* len; float* out;
};

__global__ __launch_bounds__(512) void k_loop(LoopP P){
  const int wg = blockIdx.x, tid = threadIdx.x;
  const int wv = tid>>6, lane = tid&63, lr = lane&15, lh = lane>>4;
  __shared__ __align__(16) char SMraw[34816];
  unsigned bt = 0;

  for (int t = 0; t <= 64; ++t){
    // ---------- P1: pA = h @ [Wdec|Wfb]^T ; preds/stop(t-1) ----------
    if (wg < 21){
      u16* HL = (u16*)SMraw;
      const u16* hc = (t & 1) ? P.h1 : P.h0;
      for (int i = tid; i < 4096; i += 512){
        unsigned long long v = cload_u64(((const unsigned long long*)hc) + i);
        int row = i >> 7, col = (i & 127)*4;
        *(unsigned long long*)&HL[row*520 + col] = v;
      }
      __syncthreads();
      int j0 = wg*128 + wv*16;
      f32x4 acc0 = {0,0,0,0}, acc1 = {0,0,0,0};
      #pragma unroll 4
      for (int ki = 0; ki < 16; ++ki){
        bf16x8 bv = *(const bf16x8*)&P.WAP[(size_t)(j0+lr)*512 + ki*32 + lh*8];
        bf16x8 a0 = *(const bf16x8*)&HL[lr*520 + ki*32 + lh*8];
        bf16x8 a1 = *(const bf16x8*)&HL[(16+lr)*520 + ki*32 + lh*8];
        acc0 = MF(a0, bv, acc0);
        acc1 = MF(a1, bv, acc1);
      }
      int j = j0 + lr;
      if (j < 2560){
        #pragma unroll
        for (int r = 0; r < 4; ++r){
          cstore_f32(&P.pA[(size_t)(lh*4+r)*2560 + j], acc0[r]);
          cstore_f32(&P.pA[(size_t)(lh*4+r+16)*2560 + j], acc1[r]);
        }
      } else if (j < 2563 && t > 0){
        int jj = j - 2560, tm1 = t - 1;
        #pragma unroll
        for (int r = 0; r < 4; ++r){
          #pragma unroll
          for (int hb = 0; hb < 2; ++hb){
            int b0 = lh*4 + r + hb*16;
            float val = hb ? acc1[r] : acc0[r];
            bool mk = tm1 < P.len[b0];
            if (jj < 2) P.out[O_PRED + ((size_t)b0*64 + tm1)*2 + jj] = mk ? val + P.bfc[jj] : 0.f;
            else        P.out[O_STOP + (size_t)b0*64 + tm1] =
                          mk ? 1.f/(1.f + expf(-(val + P.bstop[0]))) : 0.f;
          }
        }
      }
    }
    if (t == 64) break;
    bt += NWG; gbar(P.bar, bt);

    // ---------- P2: scores ----------
    if (wg < 32){
      int b = wg;
      if (t < P.len[b]){
        float* a2f = (float*)SMraw;
        float* wf  = a2f + 512;
        a2f[tid] = cload_f32(&P.pA[(size_t)b*2560 + tid]) + P.bdec[tid];
        wf[tid]  = P.wfull[tid];
        __syncthreads();
        #pragma unroll
        for (int pass = 0; pass < 2; ++pass){
          int task = pass*512 + tid;
          int pl = task >> 2, q = task & 3;
          float acc = 0.f;
          if (pl < 196){
            const u16* row = P.att1 + ((size_t)(b*196 + pl))*512 + q*128;
            const float* ap = a2f + q*128;
            const float* wp = wf + q*128;
            #pragma unroll 4
            for (int i = 0; i < 16; ++i){
              bf16x8 v = *(const bf16x8*)(row + i*8);
              #pragma unroll
              for (int qq = 0; qq < 8; ++qq)
                acc += fmaxf(bf2f((u16)v[qq]) + ap[i*8+qq], 0.f) * wp[i*8+qq];
            }
          }
          acc += __shfl_xor(acc, 1);
          acc += __shfl_xor(acc, 2);
          if (pl < 196 && q == 0) cstore_f32(&P.scores[b*256 + pl], acc + P.bfull[0]);
        }
      }
    }
    bt += NWG; gbar(P.bar, bt);

    // ---------- P3: softmax + awe + gate -> axa ; alphas ----------
    if (wg < 128){
      int b = wg >> 2, dc = wg & 3;
      if (t < P.len[b]){
        float* sc   = (float*)SMraw;
        float* ev   = sc + 256;
        float* redf = ev + 256;
        float* bc   = redf + 8;
        if (tid < 196) sc[tid] = cload_f32(&P.scores[b*256 + tid]);
        __syncthreads();
        float s = (tid < 196) ? sc[tid] : -1e30f;
        float m = s;
        #pragma unroll
        for (int o = 32; o; o >>= 1) m = fmaxf(m, __shfl_down(m, o));
        if (lane == 0) redf[wv] = m;
        __syncthreads();
        if (tid == 0){
          float mm = redf[0];
          for (int i = 1; i < 8; ++i) mm = fmaxf(mm, redf[i]);
          bc[0] = mm;
        }
        __syncthreads();
        float e = (tid < 196) ? expf(s - bc[0]) : 0.f;
        if (tid < 256) ev[tid] = (tid < 196) ? e : 0.f;
        float sm = e;
        #pragma unroll
        for (int o = 32; o; o >>= 1) sm += __shfl_down(sm, o);
        __syncthreads();
        if (lane == 0) redf[wv] = sm;
        __syncthreads();
        if (tid == 0){
          float ss = 0.f;
          for (int i = 0; i < 8; ++i) ss += redf[i];
          bc[1] = ss;
        }
        __syncthreads();
        float ssum = bc[1];
        int d = dc*512 + tid;
        const u16* ep = P.enc + (size_t)(b*196)*2048 + d;
        float q0=0.f, q1=0.f, q2=0.f, q3=0.f;
        #pragma unroll 2
        for (int p = 0; p < 196; p += 4){
          q0 += ev[p+0]*bf2f(ep[(size_t)(p+0)*2048]);
          q1 += ev[p+1]*bf2f(ep[(size_t)(p+1)*2048]);
          q2 += ev[p+2]*bf2f(ep[(size_t)(p+2)*2048]);
          q3 += ev[p+3]*bf2f(ep[(size_t)(p+3)*2048]);
        }
        float awe = ((q0+q1)+(q2+q3)) / ssum;
        float gp = cload_f32(&P.pA[(size_t)b*2560 + 512 + d]) + P.bfb[d];
        float gate = 1.f/(1.f + expf(-gp));
        unsigned hb16 = f2bf(gate * awe);
        unsigned po = (unsigned)__shfl_xor((int)hb16, 1);
        if ((tid & 1) == 0)
          cstore_u32(((unsigned*)P.axa) + (size_t)b*1024 + (d >> 1), hb16 | (po << 16));
        if (dc == 0 && tid < 196) P.out[O_ALPHA + ((size_t)b*64 + t)*196 + tid] = ev[tid]/ssum;
      } else {
        if (dc == 0 && tid < 196) P.out[O_ALPHA + ((size_t)b*64 + t)*196 + tid] = 0.f;
      }
    }
    bt += NWG; gbar(P.bar, bt);

    // ---------- P4: gates GEMM (K-split over waves) + LSTM update ----------
    if (wg < 128){
      float* red = (float*)SMraw;     // [8][512]
      int jp0 = wg*16;
      const u16* hc = (t & 1) ? P.h1 : P.h0;
      u16* hn = (t & 1) ? P.h0 : P.h1;
      f32x4 acc0 = {0,0,0,0}, acc1 = {0,0,0,0};
      #pragma unroll
      for (int ks = 0; ks < 10; ++ks){
        int k = wv*320 + ks*32;
        bf16x8 a0, a1, bvv;
        if (k < 2048){
          a0 = cload_bf8(&P.axa[(size_t)lr*2048 + k + lh*8]);
          a1 = cload_bf8(&P.axa[(size_t)(16+lr)*2048 + k + lh*8]);
          bvv = *(const bf16x8*)&P.WIH2[(size_t)(jp0+lr)*2048 + k + lh*8];
        } else {
          int kk = k - 2048;
          a0 = cload_bf8(&hc[(size_t)lr*512 + kk + lh*8]);
          a1 = cload_bf8(&hc[(size_t)(16+lr)*512 + kk + lh*8]);
          bvv = *(const bf16x8*)&P.WHH2[(size_t)(jp0+lr)*512 + kk + lh*8];
        }
        acc0 = MF(a0, bvv, acc0);
        acc1 = MF(a1, bvv, acc1);
      }
      #pragma unroll
      for (int r = 0; r < 4; ++r){
        red[wv*512 + ((lh*4+r) << 4) + lr]      = acc0[r];
        red[wv*512 + ((16+lh*4+r) << 4) + lr]   = acc1[r];
      }
      __syncthreads();
      {
        int idx = tid, b = idx >> 4, jl = idx & 15, e = idx & 3;
        int jp = jp0 + jl;
        float g = 0.f;
        #pragma unroll
        for (int w = 0; w < 8; ++w) g += red[w*512 + idx];
        g += P.bcomb[jp] + bf2f(P.gemb[((size_t)b*64 + t)*2048 + jp]);
        float s = (e == 2) ? tanhf(g) : 1.f/(1.f + expf(-g));
        float vb = __shfl_xor(s, 1), vc = __shfl_xor(s, 2), vd = __shfl_xor(vb, 2);
        float i_s = (e==0)?s:(e==1)?vb:(e==2)?vc:vd;
        float f_s = (e==1)?s:(e==0)?vb:(e==3)?vc:vd;
        float g_t = (e==2)?s:(e==3)?vb:(e==0)?vc:vd;
        float o_s = (e==3)?s:(e==2)?vb:(e==1)?vc:vd;
        int u = jp >> 2;
        float cold = P.c[(size_t)b*512 + u];
        unsigned hp = cload_u32((const unsigned*)(hc + (size_t)b*512 + (u & ~1)));
        float hold = bf2f((u16)((u & 1) ? (hp >> 16) : (hp & 0xFFFF)));
        bool mk = t < P.len[b];
        float cn = mk ? (f_s*cold + i_s*g_t) : cold;
        float hv = mk ? (o_s * tanhf(cn)) : hold;
        if (e == 0) P.c[(size_t)b*512 + u] = cn;
        unsigned hb = (unsigned)f2bf(hv);
        unsigned pu = (unsigned)__shfl_xor((int)hb, 4);
        if ((idx & 7) == 0)
          cstore_u32((unsigned*)(hn + (size_t)b*512 + u), hb | (pu << 16));
      }
    }
    bt += NWG; gbar(P.bar, bt);
  }
}

// ================= host launcher =================
extern "C" void kernel_launch(void* const* d_in, const int* in_sizes, int n_in,
                              void* d_out, int out_size, void* d_ws, size_t ws_size,
                              hipStream_t stream){
  (void)in_sizes; (void)n_in; (void)out_size; (void)ws_size;
  const float* enc_out   = (const float*)d_in[0];
  const float* imgs      = (const float*)d_in[1];
  const int*   seq       = (const int*)d_in[2];
  const float* seqoff    = (const float*)d_in[3];
  const int*   caplen    = (const int*)d_in[4];
  const float* W_pe      = (const float*)d_in[5];
  const float* b_pe      = (const float*)d_in[6];
  const float* W_enc_att = (const float*)d_in[7];
  const float* b_enc_att = (const float*)d_in[8];
  const float* W_dec_att = (const float*)d_in[9];
  const float* b_dec_att = (const float*)d_in[10];
  const float* w_full    = (const float*)d_in[11];
  const float* b_full    = (const float*)d_in[12];
  const float* W_init_h  = (const float*)d_in[13];
  const float* b_init_h  = (const float*)d_in[14];
  const float* W_init_c  = (const float*)d_in[15];
  const float* b_init_c  = (const float*)d_in[16];
  const float* W_fb      = (const float*)d_in[17];
  const float* b_fb      = (const float*)d_in[18];
  const float* W_ih      = (const float*)d_in[19];
  const float* b_ih      = (const float*)d_in[20];
  const float* W_hh      = (const float*)d_in[21];
  const float* b_hh      = (const float*)d_in[22];
  const float* W_fc      = (const float*)d_in[23];
  const float* b_fc      = (const float*)d_in[24];
  const float* W_stop    = (const float*)d_in[25];
  const float* b_stop    = (const float*)d_in[26];

  float* out = (float*)d_out;
  float* ws  = (float*)d_ws;
  int*   wsi = (int*)d_ws;
  u16*   us  = (u16*)d_ws;

  k_prep<<<1, 64, 0, stream>>>(caplen, wsi + WS_SORT, wsi + WS_LEN,
                               (unsigned*)(wsi + WS_BAR), out);
  k_seqoff<<<16, 256, 0, stream>>>(seqoff, wsi + WS_SORT, out);
  k_encbf<<<6272, 256, 0, stream>>>(enc_out, wsi + WS_SORT, us + US_ENC);
  k_encmean<<<256, 256, 0, stream>>>(us + US_ENC, ws + WS_ENCM);
  k_patch<<<2048, 256, 0, stream>>>(imgs, seq, wsi + WS_SORT, us + US_PATCH);
  k_embedv2<<<128, 256, 0, stream>>>(us + US_PATCH, W_pe, b_pe, us + US_EMBBF, ws + WS_EMB0);
  k_cvt2<<<7304, 256, 0, stream>>>(W_ih, W_hh, W_dec_att, W_fb, W_fc, W_stop, W_enc_att,
                                   b_ih, b_hh,
                                   us + US_WIH2, us + US_WIHE, us + US_WHH2,
                                   us + US_WAP, us + US_WEA, ws + WS_BCOMB);
  k_gemb<<<256, 256, 0, stream>>>(us + US_EMBBF, us + US_WIHE, us + US_GEMB);
  k_att1v2<<<98, 256, 0, stream>>>(us + US_ENC, us + US_WEA, b_enc_att, us + US_ATT1);
  k_init<<<32, 256, 0, stream>>>(ws + WS_ENCM, ws + WS_EMB0, W_init_h, b_init_h,
                                 W_init_c, b_init_c, us + US_H0, ws + WS_C);

  LoopP P;
  P.bar = (unsigned*)(wsi + WS_BAR);
  P.pA = ws + WS_PA; P.scores = ws + WS_SCORES; P.c = ws + WS_C;
  P.bcomb = ws + WS_BCOMB;
  P.h0 = us + US_H0; P.h1 = us + US_H1; P.axa = us + US_AXA;
  P.att1 = us + US_ATT1; P.enc = us + US_ENC; P.gemb = us + US_GEMB;
  P.WAP = us + US_WAP; P.WIH2 = us + US_WIH2; P.WHH2 = us + US_WHH2;
  P.bdec = b_dec_att; P.wfull = w_full; P.bfull = b_full; P.bfb = b_fb;
  P.bfc = b_fc; P.bstop = b_stop;
  P.len = wsi + WS_LEN; P.out = out;
  void* ka[1] = { (void*)&P };
  hipLaunchCooperativeKernel((const void*)k_loop, dim3(NWG), dim3(512), ka, 0, stream);
}